// Round 1
// baseline (2449.856 us; speedup 1.0000x reference)
//
#include <hip/hip_runtime.h>
#include <hip/hip_bf16.h>

// Problem constants
constexpr int Bb = 32;
constexpr int Ll = 1024;
constexpr int Hh = 512;

// ---------------------------------------------------------------------------
// Kernel 1: per-row dots  s0[b,l] = c[b,l,:]·c_weight,  s1[b,l] = c[b,l,:]·q_weight
// one wave per row, 4 rows per 256-thread block
__global__ __launch_bounds__(256) void k_rowdots(
    const float* __restrict__ c, const float* __restrict__ cw,
    const float* __restrict__ qw, float* __restrict__ s0, float* __restrict__ s1) {
  int row  = blockIdx.x * 4 + (threadIdx.x >> 6);   // global b*L + l
  int lane = threadIdx.x & 63;
  const float* cr = c + (size_t)row * Hh;
  float d0 = 0.f, d1 = 0.f;
#pragma unroll
  for (int i = 0; i < Hh / 64; ++i) {
    int h = lane + i * 64;
    float v = cr[h];
    d0 = fmaf(v, cw[h], d0);
    d1 = fmaf(v, qw[h], d1);
  }
#pragma unroll
  for (int off = 32; off > 0; off >>= 1) {
    d0 += __shfl_down(d0, off);
    d1 += __shfl_down(d1, off);
  }
  if (lane == 0) { s0[row] = d0; s1[row] = d1; }
}

// ---------------------------------------------------------------------------
// Kernel 2: S[b,l,m] = sum_h (c[b,l,h]*cq[h]) * c[b,m,h] + s0[b,l] + s1[b,m] + bias
// 64x64 tile per block, 256 threads, 4x4 micro-tile, k-chunks of 16.
// LDS stored transposed ([k][row]) so fragment reads are float4 (ds_read_b128).
__global__ __launch_bounds__(256) void k_sgemm(
    const float* __restrict__ c, const float* __restrict__ cq,
    const float* __restrict__ s0, const float* __restrict__ s1,
    const float* __restrict__ bias, float* __restrict__ S) {
  const int b  = blockIdx.z;
  const int l0 = blockIdx.y * 64;
  const int m0 = blockIdx.x * 64;
  const float* cb = c + (size_t)b * Ll * Hh;
  __shared__ float As[16][68];
  __shared__ float Bs[16][68];
  const int t = threadIdx.x;
  const int tx = t & 15, ty = t >> 4;
  const int lcol = t & 15;     // k within chunk
  const int lrow0 = t >> 4;    // row groups of 16
  float acc[4][4] = {};
  for (int kk = 0; kk < Hh; kk += 16) {
    float cqv = cq[kk + lcol];
#pragma unroll
    for (int r = 0; r < 4; ++r) {
      int row = lrow0 + r * 16;
      As[lcol][row] = cb[(size_t)(l0 + row) * Hh + kk + lcol] * cqv;
      Bs[lcol][row] = cb[(size_t)(m0 + row) * Hh + kk + lcol];
    }
    __syncthreads();
#pragma unroll
    for (int k = 0; k < 16; ++k) {
      float4 a4 = *(const float4*)&As[k][ty * 4];
      float4 b4 = *(const float4*)&Bs[k][tx * 4];
      float av[4] = {a4.x, a4.y, a4.z, a4.w};
      float bv[4] = {b4.x, b4.y, b4.z, b4.w};
#pragma unroll
      for (int i = 0; i < 4; ++i)
#pragma unroll
        for (int j = 0; j < 4; ++j) acc[i][j] = fmaf(av[i], bv[j], acc[i][j]);
    }
    __syncthreads();
  }
  const float bsc = bias[0];
  float s0v[4], s1v[4];
#pragma unroll
  for (int i = 0; i < 4; ++i) s0v[i] = s0[b * Ll + l0 + ty * 4 + i];
#pragma unroll
  for (int j = 0; j < 4; ++j) s1v[j] = s1[b * Ll + m0 + tx * 4 + j];
  float* Sb = S + (size_t)b * Ll * Ll;
#pragma unroll
  for (int i = 0; i < 4; ++i) {
    int l = l0 + ty * 4 + i;
    float4 o;
    o.x = acc[i][0] + s0v[i] + s1v[0] + bsc;
    o.y = acc[i][1] + s0v[i] + s1v[1] + bsc;
    o.z = acc[i][2] + s0v[i] + s1v[2] + bsc;
    o.w = acc[i][3] + s0v[i] + s1v[3] + bsc;
    *(float4*)&Sb[(size_t)l * Ll + m0 + tx * 4] = o;
  }
}

// ---------------------------------------------------------------------------
// Kernel 3: row softmax stats over m (mask on column m).  one wave per row.
__global__ __launch_bounds__(256) void k_rowstats(
    const float* __restrict__ S, const int* __restrict__ c_mask,
    float* __restrict__ rowmax, float* __restrict__ rowrcp) {
  int row  = blockIdx.x * 4 + (threadIdx.x >> 6);  // global b*L + l
  int b    = row >> 10;
  int lane = threadIdx.x & 63;
  const float* Sr = S + (size_t)row * Ll;
  const int* mk = c_mask + b * Ll;
  float vals[16];
  float mx = -INFINITY;
#pragma unroll
  for (int i = 0; i < 16; ++i) {
    int m = lane + i * 64;
    float v = mk[m] ? Sr[m] : -INFINITY;
    vals[i] = v;
    mx = fmaxf(mx, v);
  }
#pragma unroll
  for (int off = 32; off > 0; off >>= 1) mx = fmaxf(mx, __shfl_down(mx, off));
  mx = __shfl(mx, 0);
  float sum = 0.f;
#pragma unroll
  for (int i = 0; i < 16; ++i) sum += __expf(vals[i] - mx);
#pragma unroll
  for (int off = 32; off > 0; off >>= 1) sum += __shfl_down(sum, off);
  if (lane == 0) {
    rowmax[row] = mx;
    rowrcp[row] = 1.f / sum;
  }
}

// ---------------------------------------------------------------------------
// Kernel 4: col softmax stats over l (mask on row l).  one thread per column.
__global__ __launch_bounds__(256) void k_colstats(
    const float* __restrict__ S, const int* __restrict__ c_mask,
    float* __restrict__ colmax, float* __restrict__ colrcp) {
  int b = blockIdx.y;
  int m = blockIdx.x * 256 + threadIdx.x;
  const float* Sb = S + (size_t)b * Ll * Ll;
  const int* mk = c_mask + b * Ll;
  float mx = -INFINITY;
  for (int l = 0; l < Ll; ++l) {
    if (mk[l]) mx = fmaxf(mx, Sb[(size_t)l * Ll + m]);
  }
  float sum = 0.f;
  for (int l = 0; l < Ll; ++l) {
    if (mk[l]) sum += __expf(Sb[(size_t)l * Ll + m] - mx);
  }
  colmax[b * Ll + m] = mx;
  colrcp[b * Ll + m] = 1.f / sum;
}

// ---------------------------------------------------------------------------
// Kernel 5: u[b,m,h] = sum_l s2p[b,l,m] * c[b,l,h]   (s2p built on the fly)
// out tile 64(m) x 64(h); k = l in chunks of 16.
__global__ __launch_bounds__(256) void k_ugemm(
    const float* __restrict__ S, const float* __restrict__ c,
    const int* __restrict__ c_mask, const float* __restrict__ colmax,
    const float* __restrict__ colrcp, float* __restrict__ u) {
  const int b  = blockIdx.z;
  const int m0 = blockIdx.y * 64;
  const int h0 = blockIdx.x * 64;
  __shared__ float Ps[16][68];
  __shared__ float Cs[16][68];
  __shared__ float cmx[64], crc[64];
  const int t = threadIdx.x;
  if (t < 64) {
    cmx[t] = colmax[b * Ll + m0 + t];
    crc[t] = colrcp[b * Ll + m0 + t];
  }
  __syncthreads();
  const float* Sb = S + (size_t)b * Ll * Ll;
  const float* cb = c + (size_t)b * Ll * Hh;
  const int* mk = c_mask + b * Ll;
  const int tx = t & 15, ty = t >> 4;
  const int pcol = t & 63;    // m-offset (P) / h-offset (C)
  const int prow0 = t >> 6;   // wave id: row groups of 4
  float acc[4][4] = {};
  for (int l0 = 0; l0 < Ll; l0 += 16) {
#pragma unroll
    for (int r = 0; r < 4; ++r) {
      int lrow = prow0 + r * 4;
      int l = l0 + lrow;
      float sv = Sb[(size_t)l * Ll + m0 + pcol];
      Ps[lrow][pcol] = mk[l] ? __expf(sv - cmx[pcol]) * crc[pcol] : 0.f;
      Cs[lrow][pcol] = cb[(size_t)l * Hh + h0 + pcol];
    }
    __syncthreads();
#pragma unroll
    for (int k = 0; k < 16; ++k) {
      float4 a4 = *(const float4*)&Ps[k][ty * 4];
      float4 b4 = *(const float4*)&Cs[k][tx * 4];
      float av[4] = {a4.x, a4.y, a4.z, a4.w};
      float bv[4] = {b4.x, b4.y, b4.z, b4.w};
#pragma unroll
      for (int i = 0; i < 4; ++i)
#pragma unroll
        for (int j = 0; j < 4; ++j) acc[i][j] = fmaf(av[i], bv[j], acc[i][j]);
    }
    __syncthreads();
  }
  float* ub = u + (size_t)b * Ll * Hh;
#pragma unroll
  for (int i = 0; i < 4; ++i) {
    int m = m0 + ty * 4 + i;
    float4 o;
    o.x = acc[i][0]; o.y = acc[i][1]; o.z = acc[i][2]; o.w = acc[i][3];
    *(float4*)&ub[(size_t)m * Hh + h0 + tx * 4] = o;
  }
}

// ---------------------------------------------------------------------------
// Kernel 6: a = s1p@c, bvec = s1p@u (s1p on the fly), then write
// out[b,l,:] = [c | a | c*a | c*bvec]
__global__ __launch_bounds__(256) void k_abgemm(
    const float* __restrict__ S, const float* __restrict__ c,
    const float* __restrict__ u, const int* __restrict__ c_mask,
    const float* __restrict__ rowmax, const float* __restrict__ rowrcp,
    float* __restrict__ out) {
  const int b  = blockIdx.z;
  const int l0 = blockIdx.y * 64;
  const int h0 = blockIdx.x * 64;
  __shared__ float Ps[16][68];
  __shared__ float Cs[16][68];
  __shared__ float Us[16][68];
  __shared__ float rmx[64], rrc[64];
  const int t = threadIdx.x;
  if (t < 64) {
    rmx[t] = rowmax[b * Ll + l0 + t];
    rrc[t] = rowrcp[b * Ll + l0 + t];
  }
  __syncthreads();
  const float* Sb = S + (size_t)b * Ll * Ll;
  const float* cb = c + (size_t)b * Ll * Hh;
  const float* ub = u + (size_t)b * Ll * Hh;
  const int* mk = c_mask + b * Ll;
  const int tx = t & 15, ty = t >> 4;
  const int lcol = t & 15, lrow0 = t >> 4;   // for P loads
  const int ccol = t & 63, crow0 = t >> 6;   // for C/U loads
  float acc_a[4][4] = {};
  float acc_b[4][4] = {};
  for (int m0 = 0; m0 < Ll; m0 += 16) {
    int mask_c = mk[m0 + lcol];
#pragma unroll
    for (int r = 0; r < 4; ++r) {
      int lrow = lrow0 + r * 16;
      float sv = Sb[(size_t)(l0 + lrow) * Ll + m0 + lcol];
      Ps[lcol][lrow] = mask_c ? __expf(sv - rmx[lrow]) * rrc[lrow] : 0.f;
    }
#pragma unroll
    for (int r = 0; r < 4; ++r) {
      int mrow = crow0 + r * 4;
      Cs[mrow][ccol] = cb[(size_t)(m0 + mrow) * Hh + h0 + ccol];
      Us[mrow][ccol] = ub[(size_t)(m0 + mrow) * Hh + h0 + ccol];
    }
    __syncthreads();
#pragma unroll
    for (int k = 0; k < 16; ++k) {
      float4 a4 = *(const float4*)&Ps[k][ty * 4];
      float4 c4 = *(const float4*)&Cs[k][tx * 4];
      float4 u4 = *(const float4*)&Us[k][tx * 4];
      float av[4] = {a4.x, a4.y, a4.z, a4.w};
      float cv[4] = {c4.x, c4.y, c4.z, c4.w};
      float uv[4] = {u4.x, u4.y, u4.z, u4.w};
#pragma unroll
      for (int i = 0; i < 4; ++i) {
#pragma unroll
        for (int j = 0; j < 4; ++j) {
          acc_a[i][j] = fmaf(av[i], cv[j], acc_a[i][j]);
          acc_b[i][j] = fmaf(av[i], uv[j], acc_b[i][j]);
        }
      }
    }
    __syncthreads();
  }
  float* ob = out + (size_t)b * Ll * (4 * Hh);
#pragma unroll
  for (int i = 0; i < 4; ++i) {
    int l = l0 + ty * 4 + i;
    float4 cv = *(const float4*)&cb[(size_t)l * Hh + h0 + tx * 4];
    float* orow = ob + (size_t)l * (4 * Hh);
    int h = h0 + tx * 4;
    float4 av; av.x = acc_a[i][0]; av.y = acc_a[i][1]; av.z = acc_a[i][2]; av.w = acc_a[i][3];
    float4 bv; bv.x = acc_b[i][0]; bv.y = acc_b[i][1]; bv.z = acc_b[i][2]; bv.w = acc_b[i][3];
    float4 ca; ca.x = cv.x * av.x; ca.y = cv.y * av.y; ca.z = cv.z * av.z; ca.w = cv.w * av.w;
    float4 cbv; cbv.x = cv.x * bv.x; cbv.y = cv.y * bv.y; cbv.z = cv.z * bv.z; cbv.w = cv.w * bv.w;
    *(float4*)&orow[h] = cv;
    *(float4*)&orow[Hh + h] = av;
    *(float4*)&orow[2 * Hh + h] = ca;
    *(float4*)&orow[3 * Hh + h] = cbv;
  }
}

// ---------------------------------------------------------------------------
extern "C" void kernel_launch(void* const* d_in, const int* in_sizes, int n_in,
                              void* d_out, int out_size, void* d_ws, size_t ws_size,
                              hipStream_t stream) {
  const float* c        = (const float*)d_in[0];
  const int*   c_mask   = (const int*)d_in[1];
  const float* c_weight = (const float*)d_in[2];
  const float* q_weight = (const float*)d_in[3];
  const float* cq       = (const float*)d_in[4];
  const float* bias     = (const float*)d_in[5];
  float* out = (float*)d_out;

  // workspace layout
  char* ws = (char*)d_ws;
  float* S      = (float*)ws;                                   // B*L*L
  float* u      = (float*)(ws + (size_t)Bb * Ll * Ll * 4);      // B*L*H
  char*  st     = ws + (size_t)Bb * Ll * Ll * 4 + (size_t)Bb * Ll * Hh * 4;
  float* s0     = (float*)st;                 // B*L
  float* s1     = s0 + Bb * Ll;
  float* rowmax = s1 + Bb * Ll;
  float* rowrcp = rowmax + Bb * Ll;
  float* colmax = rowrcp + Bb * Ll;
  float* colrcp = colmax + Bb * Ll;

  // 1. per-row dots
  k_rowdots<<<dim3(Bb * Ll / 4), dim3(256), 0, stream>>>(c, c_weight, q_weight, s0, s1);
  // 2. S logits
  k_sgemm<<<dim3(Ll / 64, Ll / 64, Bb), dim3(256), 0, stream>>>(c, cq, s0, s1, bias, S);
  // 3. row stats
  k_rowstats<<<dim3(Bb * Ll / 4), dim3(256), 0, stream>>>(S, c_mask, rowmax, rowrcp);
  // 4. col stats
  k_colstats<<<dim3(Ll / 256, Bb), dim3(256), 0, stream>>>(S, c_mask, colmax, colrcp);
  // 5. u = s2p^T @ c
  k_ugemm<<<dim3(Hh / 64, Ll / 64, Bb), dim3(256), 0, stream>>>(S, c, c_mask, colmax, colrcp, u);
  // 6. [a|b] GEMM + epilogue
  k_abgemm<<<dim3(Hh / 64, Ll / 64, Bb), dim3(256), 0, stream>>>(S, c, u, c_mask, rowmax, rowrcp, out);
}

// Round 2
// 850.180 us; speedup vs baseline: 2.8816x; 2.8816x over previous
//
#include <hip/hip_runtime.h>
#include <hip/hip_bf16.h>
#include <stdint.h>

constexpr int Bb = 32;
constexpr int Ll = 1024;
constexpr int Hh = 512;

typedef __attribute__((ext_vector_type(8))) short short8;
typedef __attribute__((ext_vector_type(4))) short short4v;
typedef __attribute__((ext_vector_type(4))) float float4v;
typedef __attribute__((ext_vector_type(4))) int int4v;

__device__ inline short f2bf(float f) {
  union { float f; uint32_t u; } v; v.f = f;
  uint32_t r = (v.u + 0x7FFF + ((v.u >> 16) & 1)) >> 16;
  return (short)r;
}

#define MFMA(a, b, c) __builtin_amdgcn_mfma_f32_16x16x32_bf16(a, b, c, 0, 0, 0)

// async 16B global->LDS (dest = wave-uniform base + lane*16)
__device__ inline void gl_lds(const short* g, short* l) {
  __builtin_amdgcn_global_load_lds(
      (const __attribute__((address_space(1))) unsigned int*)g,
      (__attribute__((address_space(3))) unsigned int*)l, 16, 0, 0);
}

// Stage ROWS x 64 bf16 tile from row-major global (stride sk) into LDS.
// LDS layout: lds[row*64 + (kb ^ (row&7))*8 .. +8] = g[row*sk + kb*8 .. +8]
// (XOR swizzle -> both staging writes and frag reads are bank-uniform)
template <int ROWS>
__device__ inline void stage(short* lds, const short* g, int sk, int t) {
  const int w = t >> 6;
  const int kbg = (t & 7) ^ ((t >> 3) & 7);
#pragma unroll
  for (int r = 0; r < ROWS / 32; ++r) {
    int row = r * 32 + (t >> 3);
    gl_lds(g + (size_t)row * sk + kbg * 8, lds + (r * 32 + w * 8) * 64);
  }
}

// fragment load: 8 contiguous bf16 (k) for row, k-block kb (global k index kb*8)
__device__ inline short8 fld(const short* lds, int row, int kb) {
  return *(const short8*)(lds + row * 64 + ((kb ^ (row & 7)) << 3));
}

// ---------------------------------------------------------------------------
// per-row dots  s0[b,l] = c.cw,  s1[b,l] = c.qw
__global__ __launch_bounds__(256) void k_rowdots(
    const float* __restrict__ c, const float* __restrict__ cw,
    const float* __restrict__ qw, float* __restrict__ s0, float* __restrict__ s1) {
  int row = blockIdx.x * 4 + (threadIdx.x >> 6);
  int lane = threadIdx.x & 63;
  const float* cr = c + (size_t)row * Hh;
  float d0 = 0.f, d1 = 0.f;
#pragma unroll
  for (int i = 0; i < Hh / 64; ++i) {
    int h = lane + i * 64;
    float v = cr[h];
    d0 = fmaf(v, cw[h], d0);
    d1 = fmaf(v, qw[h], d1);
  }
#pragma unroll
  for (int off = 32; off > 0; off >>= 1) {
    d0 += __shfl_down(d0, off);
    d1 += __shfl_down(d1, off);
  }
  if (lane == 0) { s0[row] = d0; s1[row] = d1; }
}

// ---------------------------------------------------------------------------
// c (fp32) -> c16 (bf16), cbq16 = bf16(c*cq)
__global__ __launch_bounds__(256) void k_cvt(
    const float* __restrict__ c, const float* __restrict__ cq,
    short* __restrict__ c16, short* __restrict__ cbq16) {
  size_t i8 = ((size_t)blockIdx.x * 256 + threadIdx.x) * 8;
  int h = (int)(i8 & (Hh - 1));
  float4v v0 = *(const float4v*)&c[i8];
  float4v v1 = *(const float4v*)&c[i8 + 4];
  float4v q0 = *(const float4v*)&cq[h];
  float4v q1 = *(const float4v*)&cq[h + 4];
  short8 a, bq;
#pragma unroll
  for (int j = 0; j < 4; ++j) {
    a[j] = f2bf(v0[j]);     a[4 + j] = f2bf(v1[j]);
    bq[j] = f2bf(v0[j] * q0[j]); bq[4 + j] = f2bf(v1[j] * q1[j]);
  }
  *(short8*)&c16[i8] = a;
  *(short8*)&cbq16[i8] = bq;
}

// ---------------------------------------------------------------------------
// transpose c -> cT16[b][h][l] bf16
__global__ __launch_bounds__(256) void k_ct(const float* __restrict__ c,
                                            short* __restrict__ cT) {
  const int b = blockIdx.z, h0 = blockIdx.x * 64, l0 = blockIdx.y * 64;
  __shared__ short T[64 * 65];
  const int t = threadIdx.x, rl = t >> 4, c4 = (t & 15) * 4;
#pragma unroll
  for (int p = 0; p < 4; ++p) {
    int ll = rl + p * 16;
    float4v v = *(const float4v*)&c[((size_t)(b * Ll + l0 + ll)) * Hh + h0 + c4];
#pragma unroll
    for (int j = 0; j < 4; ++j) T[ll * 65 + c4 + j] = f2bf(v[j]);
  }
  __syncthreads();
#pragma unroll
  for (int p = 0; p < 4; ++p) {
    int hh = rl + p * 16;
    short4v o;
#pragma unroll
    for (int j = 0; j < 4; ++j) o[j] = T[(c4 + j) * 65 + hh];
    *(short4v*)&cT[((size_t)(b * Hh + h0 + hh)) * Ll + l0 + c4] = o;
  }
}

// ---------------------------------------------------------------------------
// S = cbq16 @ c16^T + s0 + s1 + bias   (fp32 out)
__global__ __launch_bounds__(256) void k_sgemm(
    const short* __restrict__ Aq, const short* __restrict__ Bc,
    const float* __restrict__ s0, const float* __restrict__ s1,
    const float* __restrict__ bias, float* __restrict__ S) {
  const int b = blockIdx.z, l0 = blockIdx.y * 128, m0 = blockIdx.x * 128;
  __shared__ __align__(16) short As[128 * 64];
  __shared__ __align__(16) short Bs[128 * 64];
  const int t = threadIdx.x, li = t & 63, w = t >> 6;
  const int wy = w >> 1, wx = w & 1, rr = li & 15, q = li >> 4;
  const short* Ag = Aq + ((size_t)b * Ll + l0) * Hh;
  const short* Bg = Bc + ((size_t)b * Ll + m0) * Hh;
  float4v acc[4][4];
#pragma unroll
  for (int i = 0; i < 4; ++i)
#pragma unroll
    for (int j = 0; j < 4; ++j) acc[i][j] = (float4v){0.f, 0.f, 0.f, 0.f};
  for (int kk = 0; kk < Hh; kk += 64) {
    stage<128>(As, Ag + kk, Hh, t);
    stage<128>(Bs, Bg + kk, Hh, t);
    __syncthreads();
#pragma unroll
    for (int ks = 0; ks < 2; ++ks) {
      int kb = ks * 4 + q;
      short8 af[4], bf4[4];
#pragma unroll
      for (int mt = 0; mt < 4; ++mt) af[mt] = fld(As, wy * 64 + mt * 16 + rr, kb);
#pragma unroll
      for (int nt = 0; nt < 4; ++nt) bf4[nt] = fld(Bs, wx * 64 + nt * 16 + rr, kb);
#pragma unroll
      for (int mt = 0; mt < 4; ++mt)
#pragma unroll
        for (int nt = 0; nt < 4; ++nt)
          acc[mt][nt] = MFMA(af[mt], bf4[nt], acc[mt][nt]);
    }
    __syncthreads();
  }
  const float bsc = bias[0];
  float* Sb = S + (size_t)b * Ll * Ll;
#pragma unroll
  for (int nt = 0; nt < 4; ++nt) {
    int m = m0 + wx * 64 + nt * 16 + rr;
    float s1v = s1[b * Ll + m] + bsc;
#pragma unroll
    for (int mt = 0; mt < 4; ++mt) {
#pragma unroll
      for (int i = 0; i < 4; ++i) {
        int l = l0 + wy * 64 + mt * 16 + q * 4 + i;
        Sb[(size_t)l * Ll + m] = acc[mt][nt][i] + s0[b * Ll + l] + s1v;
      }
    }
  }
}

// ---------------------------------------------------------------------------
// row softmax stats (mask on columns m)
__global__ __launch_bounds__(256) void k_rowstats(
    const float* __restrict__ S, const int* __restrict__ c_mask,
    float* __restrict__ rowmax, float* __restrict__ rowrcp) {
  int row = blockIdx.x * 4 + (threadIdx.x >> 6);
  int b = row >> 10;
  int lane = threadIdx.x & 63;
  const float* Sr = S + (size_t)row * Ll;
  const int* mk = c_mask + b * Ll;
  float vals[16];
  float mx = -INFINITY;
#pragma unroll
  for (int i = 0; i < 16; ++i) {
    int m = lane + i * 64;
    float v = mk[m] ? Sr[m] : -INFINITY;
    vals[i] = v;
    mx = fmaxf(mx, v);
  }
#pragma unroll
  for (int off = 32; off > 0; off >>= 1) mx = fmaxf(mx, __shfl_down(mx, off));
  mx = __shfl(mx, 0);
  float sum = 0.f;
#pragma unroll
  for (int i = 0; i < 16; ++i) sum += __expf(vals[i] - mx);
#pragma unroll
  for (int off = 32; off > 0; off >>= 1) sum += __shfl_down(sum, off);
  if (lane == 0) { rowmax[row] = mx; rowrcp[row] = 1.f / sum; }
}

// ---------------------------------------------------------------------------
// col softmax partials over l-chunks of 128 (mask on rows l)
__global__ __launch_bounds__(256) void k_colpart(
    const float* __restrict__ S, const int* __restrict__ c_mask,
    float* __restrict__ pmax, float* __restrict__ psum) {
  int b = blockIdx.z, l0 = blockIdx.y * 128;
  int m = blockIdx.x * 256 + threadIdx.x;
  const float* Sb = S + (size_t)b * Ll * Ll;
  const int* mk = c_mask + b * Ll;
  float mx = -INFINITY;
  for (int l = l0; l < l0 + 128; ++l)
    if (mk[l]) mx = fmaxf(mx, Sb[(size_t)l * Ll + m]);
  float sum = 0.f;
  if (mx > -INFINITY)
    for (int l = l0; l < l0 + 128; ++l)
      if (mk[l]) sum += __expf(Sb[(size_t)l * Ll + m] - mx);
  int o = blockIdx.y * (Bb * Ll) + b * Ll + m;
  pmax[o] = mx;
  psum[o] = sum;
}

__global__ __launch_bounds__(256) void k_colcomb(
    const float* __restrict__ pmax, const float* __restrict__ psum,
    float* __restrict__ colmax, float* __restrict__ colrcp) {
  int i = blockIdx.x * 256 + threadIdx.x;
  float M = -INFINITY;
#pragma unroll
  for (int k = 0; k < 8; ++k) M = fmaxf(M, pmax[k * (Bb * Ll) + i]);
  float s = 0.f;
#pragma unroll
  for (int k = 0; k < 8; ++k) {
    float pm = pmax[k * (Bb * Ll) + i];
    if (pm > -INFINITY) s += psum[k * (Bb * Ll) + i] * __expf(pm - M);
  }
  colmax[i] = M;
  colrcp[i] = 1.f / s;
}

// ---------------------------------------------------------------------------
// P1[b][l][m] = mask[m]*exp(S-rowmax[l])*rowrcp[l]  (bf16)
__global__ __launch_bounds__(256) void k_p1(
    const float* __restrict__ S, const int* __restrict__ c_mask,
    const float* __restrict__ rowmax, const float* __restrict__ rowrcp,
    short* __restrict__ P1) {
  size_t gi = (size_t)blockIdx.x * 256 + threadIdx.x;
  size_t idx = gi * 8;
  int row = (int)(gi >> 7);      // b*L + l
  int b = row >> 10;
  int m = ((int)gi & 127) * 8;
  float rm = rowmax[row], rr = rowrcp[row];
  int4v k0 = *(const int4v*)&c_mask[b * Ll + m];
  int4v k1 = *(const int4v*)&c_mask[b * Ll + m + 4];
  float4v v0 = *(const float4v*)&S[idx];
  float4v v1 = *(const float4v*)&S[idx + 4];
  short8 o;
#pragma unroll
  for (int j = 0; j < 4; ++j) {
    o[j] = k0[j] ? f2bf(__expf(v0[j] - rm) * rr) : (short)0;
    o[4 + j] = k1[j] ? f2bf(__expf(v1[j] - rm) * rr) : (short)0;
  }
  *(short8*)&P1[idx] = o;
}

// ---------------------------------------------------------------------------
// P2T[b][m][l] = mask[l]*exp(S[l][m]-colmax[m])*colrcp[m]  (bf16, transposed)
__global__ __launch_bounds__(256) void k_p2t(
    const float* __restrict__ S, const int* __restrict__ c_mask,
    const float* __restrict__ colmax, const float* __restrict__ colrcp,
    short* __restrict__ P2T) {
  const int b = blockIdx.z, m0 = blockIdx.x * 64, l0 = blockIdx.y * 64;
  __shared__ short T[64 * 65];
  const int t = threadIdx.x, rl = t >> 4, c4 = (t & 15) * 4;
  const float* Sb = S + (size_t)b * Ll * Ll;
  float4v cm = *(const float4v*)&colmax[b * Ll + m0 + c4];
  float4v cr = *(const float4v*)&colrcp[b * Ll + m0 + c4];
#pragma unroll
  for (int p = 0; p < 4; ++p) {
    int ll = rl + p * 16;
    int mk = c_mask[b * Ll + l0 + ll];
    float4v v = *(const float4v*)&Sb[(size_t)(l0 + ll) * Ll + m0 + c4];
#pragma unroll
    for (int j = 0; j < 4; ++j)
      T[ll * 65 + c4 + j] = mk ? f2bf(__expf(v[j] - cm[j]) * cr[j]) : (short)0;
  }
  __syncthreads();
#pragma unroll
  for (int p = 0; p < 4; ++p) {
    int mm = rl + p * 16;
    short4v o;
#pragma unroll
    for (int j = 0; j < 4; ++j) o[j] = T[(c4 + j) * 65 + mm];
    *(short4v*)&P2T[((size_t)(b * Ll + m0 + mm)) * Ll + l0 + c4] = o;
  }
}

// ---------------------------------------------------------------------------
// uT[b][h][m] = (P2T @ cT^T)^T  bf16
__global__ __launch_bounds__(256) void k_ugemm(
    const short* __restrict__ P2T, const short* __restrict__ cT,
    short* __restrict__ uT) {
  const int b = blockIdx.z, m0 = blockIdx.y * 128, h0 = blockIdx.x * 128;
  __shared__ __align__(16) short As[128 * 64];
  __shared__ __align__(16) short Bs[128 * 64];
  const int t = threadIdx.x, li = t & 63, w = t >> 6;
  const int wy = w >> 1, wx = w & 1, rr = li & 15, q = li >> 4;
  const short* Ag = P2T + ((size_t)b * Ll + m0) * Ll;
  const short* Bg = cT + ((size_t)b * Hh + h0) * Ll;
  float4v acc[4][4];
#pragma unroll
  for (int i = 0; i < 4; ++i)
#pragma unroll
    for (int j = 0; j < 4; ++j) acc[i][j] = (float4v){0.f, 0.f, 0.f, 0.f};
  for (int kk = 0; kk < Ll; kk += 64) {
    stage<128>(As, Ag + kk, Ll, t);
    stage<128>(Bs, Bg + kk, Ll, t);
    __syncthreads();
#pragma unroll
    for (int ks = 0; ks < 2; ++ks) {
      int kb = ks * 4 + q;
      short8 af[4], bf4[4];
#pragma unroll
      for (int mt = 0; mt < 4; ++mt) af[mt] = fld(As, wy * 64 + mt * 16 + rr, kb);
#pragma unroll
      for (int nt = 0; nt < 4; ++nt) bf4[nt] = fld(Bs, wx * 64 + nt * 16 + rr, kb);
#pragma unroll
      for (int mt = 0; mt < 4; ++mt)
#pragma unroll
        for (int nt = 0; nt < 4; ++nt)
          acc[mt][nt] = MFMA(af[mt], bf4[nt], acc[mt][nt]);
    }
    __syncthreads();
  }
#pragma unroll
  for (int nt = 0; nt < 4; ++nt) {
    int h = h0 + wx * 64 + nt * 16 + rr;
#pragma unroll
    for (int mt = 0; mt < 4; ++mt) {
      int mb = m0 + wy * 64 + mt * 16 + q * 4;
      short4v o;
#pragma unroll
      for (int i = 0; i < 4; ++i) o[i] = f2bf(acc[mt][nt][i]);
      *(short4v*)&uT[((size_t)b * Hh + h) * Ll + mb] = o;
    }
  }
}

// ---------------------------------------------------------------------------
// a = P1@c, bvec = P1@u; out = [c | a | c*a | c*bvec]
__global__ __launch_bounds__(256) void k_abgemm(
    const short* __restrict__ P1, const short* __restrict__ cT,
    const short* __restrict__ uT, const float* __restrict__ c,
    float* __restrict__ out) {
  const int b = blockIdx.z, l0 = blockIdx.y * 128, h0 = blockIdx.x * 64;
  __shared__ __align__(16) short As[128 * 64];
  __shared__ __align__(16) short B1s[64 * 64];
  __shared__ __align__(16) short B2s[64 * 64];
  const int t = threadIdx.x, li = t & 63, w = t >> 6;
  const int wy = w >> 1, wx = w & 1, rr = li & 15, q = li >> 4;
  const short* Ag = P1 + ((size_t)b * Ll + l0) * Ll;
  const short* B1g = cT + ((size_t)b * Hh + h0) * Ll;
  const short* B2g = uT + ((size_t)b * Hh + h0) * Ll;
  float4v aa[4][2], ab[4][2];
#pragma unroll
  for (int i = 0; i < 4; ++i)
#pragma unroll
    for (int j = 0; j < 2; ++j) {
      aa[i][j] = (float4v){0.f, 0.f, 0.f, 0.f};
      ab[i][j] = (float4v){0.f, 0.f, 0.f, 0.f};
    }
  for (int kk = 0; kk < Ll; kk += 64) {
    stage<128>(As, Ag + kk, Ll, t);
    stage<64>(B1s, B1g + kk, Ll, t);
    stage<64>(B2s, B2g + kk, Ll, t);
    __syncthreads();
#pragma unroll
    for (int ks = 0; ks < 2; ++ks) {
      int kb = ks * 4 + q;
      short8 af[4], b1[2], b2[2];
#pragma unroll
      for (int mt = 0; mt < 4; ++mt) af[mt] = fld(As, wy * 64 + mt * 16 + rr, kb);
#pragma unroll
      for (int nt = 0; nt < 2; ++nt) {
        b1[nt] = fld(B1s, wx * 32 + nt * 16 + rr, kb);
        b2[nt] = fld(B2s, wx * 32 + nt * 16 + rr, kb);
      }
#pragma unroll
      for (int mt = 0; mt < 4; ++mt)
#pragma unroll
        for (int nt = 0; nt < 2; ++nt) {
          aa[mt][nt] = MFMA(af[mt], b1[nt], aa[mt][nt]);
          ab[mt][nt] = MFMA(af[mt], b2[nt], ab[mt][nt]);
        }
    }
    __syncthreads();
  }
#pragma unroll
  for (int nt = 0; nt < 2; ++nt) {
    int h = h0 + wx * 32 + nt * 16 + rr;
#pragma unroll
    for (int mt = 0; mt < 4; ++mt) {
#pragma unroll
      for (int i = 0; i < 4; ++i) {
        int l = l0 + wy * 64 + mt * 16 + q * 4 + i;
        float cv = c[((size_t)b * Ll + l) * Hh + h];
        size_t ob = ((size_t)b * Ll + l) * (size_t)(4 * Hh);
        float av = aa[mt][nt][i], bv = ab[mt][nt][i];
        out[ob + h] = cv;
        out[ob + Hh + h] = av;
        out[ob + 2 * Hh + h] = cv * av;
        out[ob + 3 * Hh + h] = cv * bv;
      }
    }
  }
}

// ---------------------------------------------------------------------------
extern "C" void kernel_launch(void* const* d_in, const int* in_sizes, int n_in,
                              void* d_out, int out_size, void* d_ws, size_t ws_size,
                              hipStream_t stream) {
  const float* c = (const float*)d_in[0];
  const int* c_mask = (const int*)d_in[1];
  const float* c_weight = (const float*)d_in[2];
  const float* q_weight = (const float*)d_in[3];
  const float* cq = (const float*)d_in[4];
  const float* bias = (const float*)d_in[5];
  float* out = (float*)d_out;

  // workspace layout with lifetime reuse (~305 MB peak):
  //  [0,134.2M)    S fp32            -> reused by uT (bf16) after p1/p2t
  //  [134.2,167.8) cT16
  //  [167.8,201.4) c16               -> P1 low half after sgemm
  //  [201.4,234.9) cbq16             -> P1 high half after sgemm
  //  [234.9,302.0) P2T
  //  [302.0,...)   stats
  char* ws = (char*)d_ws;
  float* S = (float*)ws;
  short* uT = (short*)ws;
  short* cT16 = (short*)(ws + 134217728ull);
  short* c16 = (short*)(ws + 167772160ull);
  short* P1 = (short*)(ws + 167772160ull);
  short* cbq16 = (short*)(ws + 201326592ull);
  short* P2T = (short*)(ws + 234881024ull);
  float* st = (float*)(ws + 301989888ull);
  float* s0 = st;
  float* s1 = st + 32768;
  float* rowmax = st + 65536;
  float* rowrcp = st + 98304;
  float* colmax = st + 131072;
  float* colrcp = st + 163840;
  float* pmax = st + 196608;
  float* psum = st + 458752;

  k_rowdots<<<dim3(Bb * Ll / 4), dim3(256), 0, stream>>>(c, c_weight, q_weight, s0, s1);
  k_cvt<<<dim3(8192), dim3(256), 0, stream>>>(c, cq, c16, cbq16);
  k_ct<<<dim3(Hh / 64, Ll / 64, Bb), dim3(256), 0, stream>>>(c, cT16);
  k_sgemm<<<dim3(Ll / 128, Ll / 128, Bb), dim3(256), 0, stream>>>(cbq16, c16, s0, s1, bias, S);
  k_rowstats<<<dim3(Bb * Ll / 4), dim3(256), 0, stream>>>(S, c_mask, rowmax, rowrcp);
  k_colpart<<<dim3(Ll / 256, 8, Bb), dim3(256), 0, stream>>>(S, c_mask, pmax, psum);
  k_colcomb<<<dim3(Bb * Ll / 256), dim3(256), 0, stream>>>(pmax, psum, colmax, colrcp);
  k_p1<<<dim3(16384), dim3(256), 0, stream>>>(S, c_mask, rowmax, rowrcp, P1);
  k_p2t<<<dim3(Ll / 64, Ll / 64, Bb), dim3(256), 0, stream>>>(S, c_mask, colmax, colrcp, P2T);
  k_ugemm<<<dim3(Hh / 128, Ll / 128, Bb), dim3(256), 0, stream>>>(P2T, cT16, uT);
  k_abgemm<<<dim3(Hh / 64, Ll / 128, Bb), dim3(256), 0, stream>>>(P1, cT16, uT, c, out);
}